// Round 1
// baseline (2058.990 us; speedup 1.0000x reference)
//
#include <hip/hip_runtime.h>
#include <stdint.h>

#define BT_TOK 4096
#define EDIM 768
#define FDIM 24576

// ---------- monotone float<->uint transform (order-preserving) ----------
__device__ __forceinline__ uint32_t f2u(float f) {
    uint32_t b = __float_as_uint(f);
    return (b & 0x80000000u) ? ~b : (b | 0x80000000u);
}
__device__ __forceinline__ float u2f(uint32_t u) {
    uint32_t b = (u & 0x80000000u) ? (u & 0x7FFFFFFFu) : ~u;
    return __uint_as_float(b);
}

// ================= K1: encode GEMM =================
// lat[M=4096][N=24576] = (x - b_dec)[M][K=768] @ W_enc[K][N] + b_enc
#define BM 128
#define BN 128
#define BKK 8

__global__ __launch_bounds__(256)
void encode_gemm(const float* __restrict__ x, const float* __restrict__ Wenc,
                 const float* __restrict__ benc, const float* __restrict__ bdec,
                 float* __restrict__ lat)
{
    __shared__ float As[BKK][BM];   // [k][m]
    __shared__ float Bs[BKK][BN];   // [k][n]

    const int tid = threadIdx.x;
    const int tx = tid & 15, ty = tid >> 4;
    const int bm = blockIdx.y * BM;
    const int bn = blockIdx.x * BN;

    const int arow = tid >> 1, ac4 = (tid & 1) * 4;   // A tile: 128 rows x 8 k
    const int bkr  = tid >> 5, bc4 = (tid & 31) * 4;  // B tile: 8 k x 128 n

    float acc[8][8] = {};
    float af[8], bf[8];

    for (int k0 = 0; k0 < EDIM; k0 += BKK) {
        float4 av = *(const float4*)(x + (size_t)(bm + arow) * EDIM + k0 + ac4);
        float4 bd = *(const float4*)(bdec + k0 + ac4);
        av.x -= bd.x; av.y -= bd.y; av.z -= bd.z; av.w -= bd.w;
        float4 bv = *(const float4*)(Wenc + (size_t)(k0 + bkr) * FDIM + bn + bc4);
        __syncthreads();
        As[ac4 + 0][arow] = av.x; As[ac4 + 1][arow] = av.y;
        As[ac4 + 2][arow] = av.z; As[ac4 + 3][arow] = av.w;
        *(float4*)&Bs[bkr][bc4] = bv;
        __syncthreads();
        #pragma unroll
        for (int kk = 0; kk < BKK; ++kk) {
            *(float4*)&af[0] = *(const float4*)&As[kk][ty * 8];
            *(float4*)&af[4] = *(const float4*)&As[kk][ty * 8 + 4];
            *(float4*)&bf[0] = *(const float4*)&Bs[kk][tx * 8];
            *(float4*)&bf[4] = *(const float4*)&Bs[kk][tx * 8 + 4];
            #pragma unroll
            for (int i = 0; i < 8; ++i)
                #pragma unroll
                for (int j = 0; j < 8; ++j)
                    acc[i][j] = fmaf(af[i], bf[j], acc[i][j]);
        }
    }

    float4 be0 = *(const float4*)(benc + bn + tx * 8);
    float4 be1 = *(const float4*)(benc + bn + tx * 8 + 4);
    #pragma unroll
    for (int i = 0; i < 8; ++i) {
        size_t ro = (size_t)(bm + ty * 8 + i) * FDIM + bn + tx * 8;
        float4 o0 = make_float4(acc[i][0] + be0.x, acc[i][1] + be0.y,
                                acc[i][2] + be0.z, acc[i][3] + be0.w);
        float4 o1 = make_float4(acc[i][4] + be1.x, acc[i][5] + be1.y,
                                acc[i][6] + be1.z, acc[i][7] + be1.w);
        *(float4*)(lat + ro)     = o0;
        *(float4*)(lat + ro + 4) = o1;
    }
}

// ================= K2: top-k threshold + mask-in-place + decode =================
#define CAP 512

__global__ __launch_bounds__(256)
void topk_mask_decode(float* __restrict__ lat, const float* __restrict__ Wdec,
                      const float* __restrict__ bdec, const int* __restrict__ kptr,
                      float* __restrict__ xrec)
{
    const int row = blockIdx.x;
    const int tid = threadIdx.x;
    float* lrow = lat + (size_t)row * FDIM;
    int kk = *kptr;
    if (kk < 1) kk = 1;
    if (kk > CAP) kk = CAP;

    __shared__ uint32_t ckey[CAP];
    __shared__ uint32_t cidx[CAP];
    __shared__ float redf[256];
    __shared__ int   redi[256];
    __shared__ int   cc;

    // ---- pass A: sigma estimate ----
    float ss = 0.f;
    for (int i = tid * 4; i < FDIM; i += 1024) {
        float4 v = *(const float4*)(lrow + i);
        ss = fmaf(v.x, v.x, fmaf(v.y, v.y, fmaf(v.z, v.z, fmaf(v.w, v.w, ss))));
    }
    redf[tid] = ss;
    __syncthreads();
    for (int s = 128; s > 0; s >>= 1) { if (tid < s) redf[tid] += redf[tid + s]; __syncthreads(); }
    const float sigma = sqrtf(redf[0] / (float)FDIM);

    // ---- find kth threshold: candidate collect with bisection bracket ----
    uint32_t ulo = 0u, uhi = 0xFFFFFFFFu;
    uint32_t ut = f2u(2.7f * sigma);
    int state = 0; uint32_t kthu = 0u; int cfound = 0;

    for (int it = 0; it < 72; ++it) {
        if (uhi - ulo <= 1u) { state = 2; kthu = uhi; break; }
        if (ut <= ulo) ut = ulo + 1u;
        if (ut >= uhi) ut = uhi - 1u;
        const float t = u2f(ut);
        __syncthreads();
        if (tid == 0) cc = 0;
        __syncthreads();
        for (int i = tid * 4; i < FDIM; i += 1024) {
            float4 v = *(const float4*)(lrow + i);
            float vv[4] = {v.x, v.y, v.z, v.w};
            #pragma unroll
            for (int j = 0; j < 4; ++j) {
                if (vv[j] > t) {
                    int p = atomicAdd(&cc, 1);
                    if (p < CAP) { ckey[p] = f2u(vv[j]); cidx[p] = (uint32_t)(i + j); }
                }
            }
        }
        __syncthreads();
        const int c = cc;
        if (c >= kk && c <= CAP) { state = 1; cfound = c; break; }
        if (c < kk) uhi = ut; else ulo = ut;
        ut = ulo + ((uhi - ulo) >> 1);
    }
    if (state == 0) { state = 2; kthu = uhi; }   // paranoia: exact-bitwise fallback

    const int e0 = tid, e1 = tid + 256, e2 = tid + 512;

    if (state == 1) {
        // pad and bitonic sort (desc by key, tie asc idx) — deterministic
        for (int i = cfound + tid; i < CAP; i += 256) { ckey[i] = 0u; cidx[i] = 0u; }
        __syncthreads();
        for (int ksz = 2; ksz <= CAP; ksz <<= 1) {
            for (int j = ksz >> 1; j > 0; j >>= 1) {
                for (int i = tid; i < CAP; i += 256) {
                    const int ixj = i ^ j;
                    if (ixj > i) {
                        uint32_t ka = ckey[i], kb = ckey[ixj];
                        uint32_t ia = cidx[i], ib = cidx[ixj];
                        bool after = (ka < kb) || (ka == kb && ia > ib);
                        bool descBlock = ((i & ksz) == 0);
                        if (descBlock ? after : !after) {
                            ckey[i] = kb; ckey[ixj] = ka;
                            cidx[i] = ib; cidx[ixj] = ia;
                        }
                    }
                }
                __syncthreads();
            }
        }
        const float kthf = u2f(ckey[kk - 1]);

        // m = #candidates with value >= kth (float compare; sorted prefix)
        int lm = 0;
        for (int j2 = tid; j2 < cfound; j2 += 256) lm += (u2f(ckey[j2]) >= kthf) ? 1 : 0;
        redi[tid] = lm;
        __syncthreads();
        for (int s = 128; s > 0; s >>= 1) { if (tid < s) redi[tid] += redi[tid + s]; __syncthreads(); }
        const int m = redi[0];

        // zero the whole row, then scatter the selected values back
        const float4 z4 = make_float4(0.f, 0.f, 0.f, 0.f);
        for (int i = tid * 4; i < FDIM; i += 1024) *(float4*)(lrow + i) = z4;
        __syncthreads();
        for (int j2 = tid; j2 < m; j2 += 256) lrow[cidx[j2]] = u2f(ckey[j2]);

        // decode from the LDS list: x_rec = sum_f v_f * W_dec[f, :] + b_dec
        float a0 = 0.f, a1 = 0.f, a2 = 0.f;
        for (int j2 = 0; j2 < m; ++j2) {
            const float v = u2f(ckey[j2]);
            const float* wr = Wdec + (size_t)cidx[j2] * EDIM;
            a0 = fmaf(v, wr[e0], a0);
            a1 = fmaf(v, wr[e1], a1);
            a2 = fmaf(v, wr[e2], a2);
        }
        xrec[(size_t)row * EDIM + e0] = a0 + bdec[e0];
        xrec[(size_t)row * EDIM + e1] = a1 + bdec[e1];
        xrec[(size_t)row * EDIM + e2] = a2 + bdec[e2];
    } else {
        // degenerate/tie-heavy fallback: exact threshold from collapsed bracket,
        // chunked mask + decode (correct for any data, incl. massive ties)
        const float kthf = u2f(kthu);
        float a0 = 0.f, a1 = 0.f, a2 = 0.f;
        for (int base = 0; base < FDIM; base += 512) {
            __syncthreads();
            if (tid == 0) cc = 0;
            __syncthreads();
            const int i = base + tid * 2;
            float2 v = *(const float2*)(lrow + i);
            float2 o;
            o.x = (v.x >= kthf) ? v.x : 0.f;
            o.y = (v.y >= kthf) ? v.y : 0.f;
            *(float2*)(lrow + i) = o;
            if (v.x >= kthf) { int p = atomicAdd(&cc, 1); ckey[p] = __float_as_uint(v.x); cidx[p] = (uint32_t)i; }
            if (v.y >= kthf) { int p = atomicAdd(&cc, 1); ckey[p] = __float_as_uint(v.y); cidx[p] = (uint32_t)(i + 1); }
            __syncthreads();
            const int c = cc;
            for (int j2 = 0; j2 < c; ++j2) {
                const float v2 = __uint_as_float(ckey[j2]);
                const float* wr = Wdec + (size_t)cidx[j2] * EDIM;
                a0 = fmaf(v2, wr[e0], a0);
                a1 = fmaf(v2, wr[e1], a1);
                a2 = fmaf(v2, wr[e2], a2);
            }
        }
        xrec[(size_t)row * EDIM + e0] = a0 + bdec[e0];
        xrec[(size_t)row * EDIM + e1] = a1 + bdec[e1];
        xrec[(size_t)row * EDIM + e2] = a2 + bdec[e2];
    }
}

extern "C" void kernel_launch(void* const* d_in, const int* in_sizes, int n_in,
                              void* d_out, int out_size, void* d_ws, size_t ws_size,
                              hipStream_t stream) {
    const float* x    = (const float*)d_in[0];
    const float* Wenc = (const float*)d_in[1];
    const float* Wdec = (const float*)d_in[2];
    const float* benc = (const float*)d_in[3];
    const float* bdec = (const float*)d_in[4];
    const int*   kptr = (const int*)d_in[5];

    float* xrec = (float*)d_out;                          // (4096, 768)
    float* fm   = (float*)d_out + (size_t)BT_TOK * EDIM;  // (4096, 24576) — also latent scratch

    dim3 g1(FDIM / BN, BT_TOK / BM);   // (192, 32)
    encode_gemm<<<g1, 256, 0, stream>>>(x, Wenc, benc, bdec, fm);
    topk_mask_decode<<<BT_TOK, 256, 0, stream>>>(fm, Wdec, bdec, kptr, xrec);
}

// Round 2
// 886.199 us; speedup vs baseline: 2.3234x; 2.3234x over previous
//
#include <hip/hip_runtime.h>
#include <stdint.h>

#define BT_TOK 4096
#define EDIM 768
#define FDIM 24576

// ---------- monotone float<->uint transform (order-preserving) ----------
__device__ __forceinline__ uint32_t f2u(float f) {
    uint32_t b = __float_as_uint(f);
    return (b & 0x80000000u) ? ~b : (b | 0x80000000u);
}
__device__ __forceinline__ float u2f(uint32_t u) {
    uint32_t b = (u & 0x80000000u) ? (u & 0x7FFFFFFFu) : ~u;
    return __uint_as_float(b);
}
__device__ __forceinline__ unsigned short f2bf_rne(float f) {
    uint32_t u = __float_as_uint(f);
    uint32_t r = (u + 0x7FFFu + ((u >> 16) & 1u)) >> 16;
    return (unsigned short)r;
}

// ============================================================
// NEW PATH: bf16-MFMA encode + fp64-band-exact top-k
// ============================================================

// ---- K0a: A = bf16(x - b_dec), [4096][768] ----
__global__ __launch_bounds__(256)
void build_A(const float* __restrict__ x, const float* __restrict__ bdec,
             unsigned short* __restrict__ Abf)
{
    const int i4 = (blockIdx.x * 256 + threadIdx.x) * 4;
    const int col = i4 % EDIM;
    float4 v = *(const float4*)(x + i4);
    float4 b = *(const float4*)(bdec + col);
    ushort4 o;
    o.x = f2bf_rne(v.x - b.x); o.y = f2bf_rne(v.y - b.y);
    o.z = f2bf_rne(v.z - b.z); o.w = f2bf_rne(v.w - b.w);
    *(ushort4*)(Abf + i4) = o;
}

// ---- K0b: W_enc [768][24576] -> WT fp32 [24576][768] + BT bf16 [24576][768] ----
#define TT 64
__global__ __launch_bounds__(256)
void build_BT(const float* __restrict__ Wenc, float* __restrict__ WTf,
              unsigned short* __restrict__ BTbf)
{
    __shared__ float tile[TT][TT + 4];   // stride 68 floats = 272 B (16B-aligned rows)
    const int n0 = blockIdx.x * TT, k0 = blockIdx.y * TT;
    const int t = threadIdx.x;

    const int krow = t >> 2, cseg = (t & 3) * 16;
    const float* src = Wenc + (size_t)(k0 + krow) * FDIM + n0 + cseg;
    float4 a0 = *(const float4*)(src);
    float4 a1 = *(const float4*)(src + 4);
    float4 a2 = *(const float4*)(src + 8);
    float4 a3 = *(const float4*)(src + 12);
    *(float4*)&tile[krow][cseg]      = a0;
    *(float4*)&tile[krow][cseg + 4]  = a1;
    *(float4*)&tile[krow][cseg + 8]  = a2;
    *(float4*)&tile[krow][cseg + 12] = a3;
    __syncthreads();

    const int nrow = t >> 2, kseg = (t & 3) * 16;
    float vals[16];
    #pragma unroll
    for (int i = 0; i < 16; ++i) vals[i] = tile[kseg + i][nrow];
    const size_t orow = (size_t)(n0 + nrow) * EDIM + k0 + kseg;
    #pragma unroll
    for (int i = 0; i < 16; i += 4)
        *(float4*)(WTf + orow + i) = make_float4(vals[i], vals[i+1], vals[i+2], vals[i+3]);
    #pragma unroll
    for (int i = 0; i < 16; i += 4) {
        ushort4 o;
        o.x = f2bf_rne(vals[i]); o.y = f2bf_rne(vals[i+1]);
        o.z = f2bf_rne(vals[i+2]); o.w = f2bf_rne(vals[i+3]);
        *(ushort4*)(BTbf + orow + i) = o;
    }
}

// ---- K1: bf16 MFMA encode GEMM: lat[m][n] = sum_k A[m][k]*BT[n][k] + benc[n] ----
typedef short bf16x8 __attribute__((ext_vector_type(8)));
typedef float f32x4  __attribute__((ext_vector_type(4)));

__device__ __forceinline__ void gld16(const unsigned short* g, short* l) {
    __builtin_amdgcn_global_load_lds(
        (const __attribute__((address_space(1))) void*)g,
        (__attribute__((address_space(3))) void*)l, 16, 0, 0);
}

#define GBM 128
#define GBN 128

__global__ __launch_bounds__(256)
void encode_bf16(const unsigned short* __restrict__ A,   // [4096][768]
                 const unsigned short* __restrict__ BT,  // [24576][768]
                 const float* __restrict__ benc,
                 float* __restrict__ lat)
{
    __shared__ short As[4 * 128 * 8];   // [kgroup][row][8] bf16 = 8 KB
    __shared__ short Bs[4 * 128 * 8];

    const int tid = threadIdx.x;
    const int l = tid & 63, w = tid >> 6;
    const int wrow = (w >> 1) * 64, wcol = (w & 1) * 64;
    const int lr = l & 15, lg = l >> 4;
    const int bm = blockIdx.y * GBM, bn = blockIdx.x * GBN;

    // staging address precompute: linear idx = round*256 + tid -> (g, row)
    const int idx0 = tid, idx1 = tid + 256;
    const int g0 = idx0 >> 7, r0 = idx0 & 127;
    const int g1 = idx1 >> 7, r1 = idx1 & 127;
    const unsigned short* ga0 = A  + (size_t)(bm + r0) * EDIM + g0 * 8;
    const unsigned short* ga1 = A  + (size_t)(bm + r1) * EDIM + g1 * 8;
    const unsigned short* gb0 = BT + (size_t)(bn + r0) * EDIM + g0 * 8;
    const unsigned short* gb1 = BT + (size_t)(bn + r1) * EDIM + g1 * 8;
    short* lA0 = As + (size_t)(w * 64) * 8;
    short* lA1 = As + (size_t)(256 + w * 64) * 8;
    short* lB0 = Bs + (size_t)(w * 64) * 8;
    short* lB1 = Bs + (size_t)(256 + w * 64) * 8;

    f32x4 acc[4][4];
    #pragma unroll
    for (int i = 0; i < 4; ++i)
        #pragma unroll
        for (int j = 0; j < 4; ++j)
            acc[i][j] = (f32x4){0.f, 0.f, 0.f, 0.f};

    for (int kt = 0; kt < EDIM / 32; ++kt) {
        __syncthreads();
        gld16(ga0 + kt * 32, lA0);
        gld16(ga1 + kt * 32, lA1);
        gld16(gb0 + kt * 32, lB0);
        gld16(gb1 + kt * 32, lB1);
        __syncthreads();

        bf16x8 af[4], bfr[4];
        #pragma unroll
        for (int f = 0; f < 4; ++f) {
            af[f]  = *(const bf16x8*)&As[(lg * 128 + wrow + f * 16 + lr) * 8];
            bfr[f] = *(const bf16x8*)&Bs[(lg * 128 + wcol + f * 16 + lr) * 8];
        }
        #pragma unroll
        for (int fi = 0; fi < 4; ++fi)
            #pragma unroll
            for (int fj = 0; fj < 4; ++fj)
                acc[fi][fj] = __builtin_amdgcn_mfma_f32_16x16x32_bf16(
                    af[fi], bfr[fj], acc[fi][fj], 0, 0, 0);
    }

    float bev[4];
    #pragma unroll
    for (int fj = 0; fj < 4; ++fj) bev[fj] = benc[bn + wcol + fj * 16 + lr];

    #pragma unroll
    for (int fi = 0; fi < 4; ++fi) {
        #pragma unroll
        for (int q = 0; q < 4; ++q) {
            const size_t ro = (size_t)(bm + wrow + fi * 16 + lg * 4 + q) * FDIM + bn + wcol;
            #pragma unroll
            for (int fj = 0; fj < 4; ++fj)
                lat[ro + fj * 16 + lr] = acc[fi][fj][q] + bev[fj];
        }
    }
}

// ---- K2: top-k with fp64-exact band refinement, mask in place, decode ----
#define CAP 512
#define BANDCAP 160
#define T0 0.6f
#define DELTA2 0.012f

__global__ __launch_bounds__(256)
void topk_band_decode(float* __restrict__ lat, const float* __restrict__ x,
                      const float* __restrict__ WTf, const float* __restrict__ Wdec,
                      const float* __restrict__ benc, const float* __restrict__ bdec,
                      const int* __restrict__ kptr, float* __restrict__ xrec)
{
    const int row = blockIdx.x;
    const int tid = threadIdx.x;
    float* lrow = lat + (size_t)row * FDIM;
    const float* xr = x + (size_t)row * EDIM;
    int kk = *kptr;
    if (kk < 1) kk = 1;
    if (kk > CAP) kk = CAP;

    __shared__ uint32_t ckey[CAP];
    __shared__ uint32_t cidx[CAP];
    __shared__ double   exd[BANDCAP];
    __shared__ int      ssel[BANDCAP];
    __shared__ int      slist[BANDCAP];
    __shared__ int      redi[256];
    __shared__ int      cc, nsel_s;

    // ---- candidate collect: fixed T0 with u-space bisection fallback ----
    uint32_t ulo = 0u, uhi = 0xFFFFFFFFu;
    uint32_t ut = f2u(T0);
    int state = 0; uint32_t kthu = 0u; int cfound = 0;

    for (int it = 0; it < 72; ++it) {
        if (uhi - ulo <= 1u) { state = 2; kthu = uhi; break; }
        if (ut <= ulo) ut = ulo + 1u;
        if (ut >= uhi) ut = uhi - 1u;
        const float t = u2f(ut);
        __syncthreads();
        if (tid == 0) cc = 0;
        __syncthreads();
        for (int i = tid * 4; i < FDIM; i += 1024) {
            float4 v = *(const float4*)(lrow + i);
            float vv[4] = {v.x, v.y, v.z, v.w};
            #pragma unroll
            for (int j = 0; j < 4; ++j) {
                if (vv[j] > t) {
                    int p = atomicAdd(&cc, 1);
                    if (p < CAP) { ckey[p] = f2u(vv[j]); cidx[p] = (uint32_t)(i + j); }
                }
            }
        }
        __syncthreads();
        const int c = cc;
        if (c >= kk && c <= CAP) { state = 1; cfound = c; break; }
        if (c < kk) uhi = ut; else ulo = ut;
        ut = ulo + ((uhi - ulo) >> 1);
    }
    if (state == 0) { state = 2; kthu = uhi; }

    const int e0 = tid, e1 = tid + 256, e2 = tid + 512;

    if (state == 1) {
        // pad + bitonic sort desc by key (tie asc idx) — deterministic
        for (int i = cfound + tid; i < CAP; i += 256) { ckey[i] = 0u; cidx[i] = 0u; }
        __syncthreads();
        for (int ksz = 2; ksz <= CAP; ksz <<= 1) {
            for (int j = ksz >> 1; j > 0; j >>= 1) {
                for (int i = tid; i < CAP; i += 256) {
                    const int ixj = i ^ j;
                    if (ixj > i) {
                        uint32_t ka = ckey[i], kb = ckey[ixj];
                        uint32_t ia = cidx[i], ib = cidx[ixj];
                        bool after = (ka < kb) || (ka == kb && ia > ib);
                        bool descBlock = ((i & ksz) == 0);
                        if (descBlock ? after : !after) {
                            ckey[i] = kb; ckey[ixj] = ka;
                            cidx[i] = ib; cidx[ixj] = ia;
                        }
                    }
                }
                __syncthreads();
            }
        }

        // ---- band: approx >= t32 - DELTA2 contains the exact top-k ----
        const float t32 = u2f(ckey[kk - 1]);
        const float blo = t32 - DELTA2;
        int lm = 0;
        for (int j = tid; j < cfound; j += 256) lm += (u2f(ckey[j]) >= blo) ? 1 : 0;
        redi[tid] = lm;
        __syncthreads();
        for (int s = 128; s > 0; s >>= 1) { if (tid < s) redi[tid] += redi[tid + s]; __syncthreads(); }
        int nb = redi[0];
        if (nb > BANDCAP) nb = BANDCAP;
        if (nb < kk) nb = (cfound < kk) ? cfound : kk;
        __syncthreads();

        // ---- fp64-exact recompute of band members ----
        const int wv = tid >> 6, ln = tid & 63;
        for (int j = wv; j < nb; j += 4) {
            const float* wt = WTf + (size_t)cidx[j] * EDIM;
            double a = 0.0;
            for (int e = ln; e < EDIM; e += 64)
                a += ((double)xr[e] - (double)bdec[e]) * (double)wt[e];
            #pragma unroll
            for (int s = 32; s > 0; s >>= 1) a += __shfl_down(a, s, 64);
            if (ln == 0) exd[j] = a + (double)benc[cidx[j]];
        }
        __syncthreads();

        // ---- exact rank selection (stable, deterministic) ----
        for (int j = tid; j < nb; j += 256) {
            const double vj = exd[j];
            int rank = 0;
            for (int i = 0; i < nb; ++i) {
                const double vi = exd[i];
                rank += (vi > vj || (vi == vj && i < j)) ? 1 : 0;
            }
            ssel[j] = (rank < kk) ? 1 : 0;
        }
        __syncthreads();
        if (tid == 0) {
            int c = 0;
            for (int j = 0; j < nb; ++j) if (ssel[j]) slist[c++] = j;
            nsel_s = c;
        }
        __syncthreads();
        const int nsel = nsel_s;

        // ---- zero row + scatter selected (approx values) ----
        const float4 z4 = make_float4(0.f, 0.f, 0.f, 0.f);
        for (int i = tid * 4; i < FDIM; i += 1024) *(float4*)(lrow + i) = z4;
        __syncthreads();
        for (int j = tid; j < nsel; j += 256) {
            const int q = slist[j];
            lrow[cidx[q]] = u2f(ckey[q]);
        }

        // ---- decode ----
        float a0 = 0.f, a1 = 0.f, a2 = 0.f;
        for (int j = 0; j < nsel; ++j) {
            const int q = slist[j];
            const float v = u2f(ckey[q]);
            const float* wr = Wdec + (size_t)cidx[q] * EDIM;
            a0 = fmaf(v, wr[e0], a0);
            a1 = fmaf(v, wr[e1], a1);
            a2 = fmaf(v, wr[e2], a2);
        }
        xrec[(size_t)row * EDIM + e0] = a0 + bdec[e0];
        xrec[(size_t)row * EDIM + e1] = a1 + bdec[e1];
        xrec[(size_t)row * EDIM + e2] = a2 + bdec[e2];
    } else {
        // degenerate fallback (massive ties): exact bitwise threshold, chunked
        const float kthf = u2f(kthu);
        float a0 = 0.f, a1 = 0.f, a2 = 0.f;
        for (int base = 0; base < FDIM; base += 512) {
            __syncthreads();
            if (tid == 0) cc = 0;
            __syncthreads();
            const int i = base + tid * 2;
            float2 v = *(const float2*)(lrow + i);
            float2 o;
            o.x = (v.x >= kthf) ? v.x : 0.f;
            o.y = (v.y >= kthf) ? v.y : 0.f;
            *(float2*)(lrow + i) = o;
            if (v.x >= kthf) { int p = atomicAdd(&cc, 1); ckey[p] = __float_as_uint(v.x); cidx[p] = (uint32_t)i; }
            if (v.y >= kthf) { int p = atomicAdd(&cc, 1); ckey[p] = __float_as_uint(v.y); cidx[p] = (uint32_t)(i + 1); }
            __syncthreads();
            const int c = cc;
            for (int j2 = 0; j2 < c; ++j2) {
                const float v2 = __uint_as_float(ckey[j2]);
                const float* wr = Wdec + (size_t)cidx[j2] * EDIM;
                a0 = fmaf(v2, wr[e0], a0);
                a1 = fmaf(v2, wr[e1], a1);
                a2 = fmaf(v2, wr[e2], a2);
            }
        }
        xrec[(size_t)row * EDIM + e0] = a0 + bdec[e0];
        xrec[(size_t)row * EDIM + e1] = a1 + bdec[e1];
        xrec[(size_t)row * EDIM + e2] = a2 + bdec[e2];
    }
}

// ============================================================
// FALLBACK PATH (ws too small): round-1 fp32 kernels, verbatim
// ============================================================
#define BM 128
#define BN 128
#define BKK 8

__global__ __launch_bounds__(256)
void encode_gemm(const float* __restrict__ x, const float* __restrict__ Wenc,
                 const float* __restrict__ benc, const float* __restrict__ bdec,
                 float* __restrict__ lat)
{
    __shared__ float Asf[BKK][BM];
    __shared__ float Bsf[BKK][BN];

    const int tid = threadIdx.x;
    const int tx = tid & 15, ty = tid >> 4;
    const int bm = blockIdx.y * BM;
    const int bn = blockIdx.x * BN;

    const int arow = tid >> 1, ac4 = (tid & 1) * 4;
    const int bkr  = tid >> 5, bc4 = (tid & 31) * 4;

    float acc[8][8] = {};
    float af[8], bf[8];

    for (int k0 = 0; k0 < EDIM; k0 += BKK) {
        float4 av = *(const float4*)(x + (size_t)(bm + arow) * EDIM + k0 + ac4);
        float4 bd = *(const float4*)(bdec + k0 + ac4);
        av.x -= bd.x; av.y -= bd.y; av.z -= bd.z; av.w -= bd.w;
        float4 bv = *(const float4*)(Wenc + (size_t)(k0 + bkr) * FDIM + bn + bc4);
        __syncthreads();
        Asf[ac4 + 0][arow] = av.x; Asf[ac4 + 1][arow] = av.y;
        Asf[ac4 + 2][arow] = av.z; Asf[ac4 + 3][arow] = av.w;
        *(float4*)&Bsf[bkr][bc4] = bv;
        __syncthreads();
        #pragma unroll
        for (int kkk = 0; kkk < BKK; ++kkk) {
            *(float4*)&af[0] = *(const float4*)&Asf[kkk][ty * 8];
            *(float4*)&af[4] = *(const float4*)&Asf[kkk][ty * 8 + 4];
            *(float4*)&bf[0] = *(const float4*)&Bsf[kkk][tx * 8];
            *(float4*)&bf[4] = *(const float4*)&Bsf[kkk][tx * 8 + 4];
            #pragma unroll
            for (int i = 0; i < 8; ++i)
                #pragma unroll
                for (int j = 0; j < 8; ++j)
                    acc[i][j] = fmaf(af[i], bf[j], acc[i][j]);
        }
    }

    float4 be0 = *(const float4*)(benc + bn + tx * 8);
    float4 be1 = *(const float4*)(benc + bn + tx * 8 + 4);
    #pragma unroll
    for (int i = 0; i < 8; ++i) {
        size_t ro = (size_t)(bm + ty * 8 + i) * FDIM + bn + tx * 8;
        float4 o0 = make_float4(acc[i][0] + be0.x, acc[i][1] + be0.y,
                                acc[i][2] + be0.z, acc[i][3] + be0.w);
        float4 o1 = make_float4(acc[i][4] + be1.x, acc[i][5] + be1.y,
                                acc[i][6] + be1.z, acc[i][7] + be1.w);
        *(float4*)(lat + ro)     = o0;
        *(float4*)(lat + ro + 4) = o1;
    }
}

__global__ __launch_bounds__(256)
void topk_mask_decode(float* __restrict__ lat, const float* __restrict__ Wdec,
                      const float* __restrict__ bdec, const int* __restrict__ kptr,
                      float* __restrict__ xrec)
{
    const int row = blockIdx.x;
    const int tid = threadIdx.x;
    float* lrow = lat + (size_t)row * FDIM;
    int kk = *kptr;
    if (kk < 1) kk = 1;
    if (kk > CAP) kk = CAP;

    __shared__ uint32_t ckey[CAP];
    __shared__ uint32_t cidx[CAP];
    __shared__ float redf[256];
    __shared__ int   redi[256];
    __shared__ int   cc;

    float ss = 0.f;
    for (int i = tid * 4; i < FDIM; i += 1024) {
        float4 v = *(const float4*)(lrow + i);
        ss = fmaf(v.x, v.x, fmaf(v.y, v.y, fmaf(v.z, v.z, fmaf(v.w, v.w, ss))));
    }
    redf[tid] = ss;
    __syncthreads();
    for (int s = 128; s > 0; s >>= 1) { if (tid < s) redf[tid] += redf[tid + s]; __syncthreads(); }
    const float sigma = sqrtf(redf[0] / (float)FDIM);

    uint32_t ulo = 0u, uhi = 0xFFFFFFFFu;
    uint32_t ut = f2u(2.7f * sigma);
    int state = 0; uint32_t kthu = 0u; int cfound = 0;

    for (int it = 0; it < 72; ++it) {
        if (uhi - ulo <= 1u) { state = 2; kthu = uhi; break; }
        if (ut <= ulo) ut = ulo + 1u;
        if (ut >= uhi) ut = uhi - 1u;
        const float t = u2f(ut);
        __syncthreads();
        if (tid == 0) cc = 0;
        __syncthreads();
        for (int i = tid * 4; i < FDIM; i += 1024) {
            float4 v = *(const float4*)(lrow + i);
            float vv[4] = {v.x, v.y, v.z, v.w};
            #pragma unroll
            for (int j = 0; j < 4; ++j) {
                if (vv[j] > t) {
                    int p = atomicAdd(&cc, 1);
                    if (p < CAP) { ckey[p] = f2u(vv[j]); cidx[p] = (uint32_t)(i + j); }
                }
            }
        }
        __syncthreads();
        const int c = cc;
        if (c >= kk && c <= CAP) { state = 1; cfound = c; break; }
        if (c < kk) uhi = ut; else ulo = ut;
        ut = ulo + ((uhi - ulo) >> 1);
    }
    if (state == 0) { state = 2; kthu = uhi; }

    const int e0 = tid, e1 = tid + 256, e2 = tid + 512;

    if (state == 1) {
        for (int i = cfound + tid; i < CAP; i += 256) { ckey[i] = 0u; cidx[i] = 0u; }
        __syncthreads();
        for (int ksz = 2; ksz <= CAP; ksz <<= 1) {
            for (int j = ksz >> 1; j > 0; j >>= 1) {
                for (int i = tid; i < CAP; i += 256) {
                    const int ixj = i ^ j;
                    if (ixj > i) {
                        uint32_t ka = ckey[i], kb = ckey[ixj];
                        uint32_t ia = cidx[i], ib = cidx[ixj];
                        bool after = (ka < kb) || (ka == kb && ia > ib);
                        bool descBlock = ((i & ksz) == 0);
                        if (descBlock ? after : !after) {
                            ckey[i] = kb; ckey[ixj] = ka;
                            cidx[i] = ib; cidx[ixj] = ia;
                        }
                    }
                }
                __syncthreads();
            }
        }
        const float kthf = u2f(ckey[kk - 1]);

        int lm = 0;
        for (int j2 = tid; j2 < cfound; j2 += 256) lm += (u2f(ckey[j2]) >= kthf) ? 1 : 0;
        redi[tid] = lm;
        __syncthreads();
        for (int s = 128; s > 0; s >>= 1) { if (tid < s) redi[tid] += redi[tid + s]; __syncthreads(); }
        const int m = redi[0];

        const float4 z4 = make_float4(0.f, 0.f, 0.f, 0.f);
        for (int i = tid * 4; i < FDIM; i += 1024) *(float4*)(lrow + i) = z4;
        __syncthreads();
        for (int j2 = tid; j2 < m; j2 += 256) lrow[cidx[j2]] = u2f(ckey[j2]);

        float a0 = 0.f, a1 = 0.f, a2 = 0.f;
        for (int j2 = 0; j2 < m; ++j2) {
            const float v = u2f(ckey[j2]);
            const float* wr = Wdec + (size_t)cidx[j2] * EDIM;
            a0 = fmaf(v, wr[e0], a0);
            a1 = fmaf(v, wr[e1], a1);
            a2 = fmaf(v, wr[e2], a2);
        }
        xrec[(size_t)row * EDIM + e0] = a0 + bdec[e0];
        xrec[(size_t)row * EDIM + e1] = a1 + bdec[e1];
        xrec[(size_t)row * EDIM + e2] = a2 + bdec[e2];
    } else {
        const float kthf = u2f(kthu);
        float a0 = 0.f, a1 = 0.f, a2 = 0.f;
        for (int base = 0; base < FDIM; base += 512) {
            __syncthreads();
            if (tid == 0) cc = 0;
            __syncthreads();
            const int i = base + tid * 2;
            float2 v = *(const float2*)(lrow + i);
            float2 o;
            o.x = (v.x >= kthf) ? v.x : 0.f;
            o.y = (v.y >= kthf) ? v.y : 0.f;
            *(float2*)(lrow + i) = o;
            if (v.x >= kthf) { int p = atomicAdd(&cc, 1); ckey[p] = __float_as_uint(v.x); cidx[p] = (uint32_t)i; }
            if (v.y >= kthf) { int p = atomicAdd(&cc, 1); ckey[p] = __float_as_uint(v.y); cidx[p] = (uint32_t)(i + 1); }
            __syncthreads();
            const int c = cc;
            for (int j2 = 0; j2 < c; ++j2) {
                const float v2 = __uint_as_float(ckey[j2]);
                const float* wr = Wdec + (size_t)cidx[j2] * EDIM;
                a0 = fmaf(v2, wr[e0], a0);
                a1 = fmaf(v2, wr[e1], a1);
                a2 = fmaf(v2, wr[e2], a2);
            }
        }
        xrec[(size_t)row * EDIM + e0] = a0 + bdec[e0];
        xrec[(size_t)row * EDIM + e1] = a1 + bdec[e1];
        xrec[(size_t)row * EDIM + e2] = a2 + bdec[e2];
    }
}

// ============================================================
extern "C" void kernel_launch(void* const* d_in, const int* in_sizes, int n_in,
                              void* d_out, int out_size, void* d_ws, size_t ws_size,
                              hipStream_t stream) {
    const float* x    = (const float*)d_in[0];
    const float* Wenc = (const float*)d_in[1];
    const float* Wdec = (const float*)d_in[2];
    const float* benc = (const float*)d_in[3];
    const float* bdec = (const float*)d_in[4];
    const int*   kptr = (const int*)d_in[5];

    float* xrec = (float*)d_out;                          // (4096, 768)
    float* fm   = (float*)d_out + (size_t)BT_TOK * EDIM;  // (4096, 24576) — latent scratch

    const size_t szA  = (size_t)BT_TOK * EDIM * 2;        //  6,291,456
    const size_t szBT = (size_t)FDIM * EDIM * 2;          // 37,748,736
    const size_t szWT = (size_t)FDIM * EDIM * 4;          // 75,497,472

    if (ws_size >= szA + szBT + szWT) {
        unsigned short* Abf  = (unsigned short*)d_ws;
        unsigned short* BTbf = (unsigned short*)((char*)d_ws + szA);
        float*          WTf  = (float*)((char*)d_ws + szA + szBT);

        build_A<<<(BT_TOK * EDIM) / 1024, 256, 0, stream>>>(x, bdec, Abf);
        build_BT<<<dim3(FDIM / TT, EDIM / TT), 256, 0, stream>>>(Wenc, WTf, BTbf);
        encode_bf16<<<dim3(FDIM / GBN, BT_TOK / GBM), 256, 0, stream>>>(Abf, BTbf, benc, fm);
        topk_band_decode<<<BT_TOK, 256, 0, stream>>>(fm, x, WTf, Wdec, benc, bdec, kptr, xrec);
    } else {
        dim3 g1(FDIM / BN, BT_TOK / BM);
        encode_gemm<<<g1, 256, 0, stream>>>(x, Wenc, benc, bdec, fm);
        topk_mask_decode<<<BT_TOK, 256, 0, stream>>>(fm, Wdec, bdec, kptr, xrec);
    }
}